// Round 3
// baseline (162.847 us; speedup 1.0000x reference)
//
#include <hip/hip_runtime.h>
#include <hip/hip_bf16.h>

#define S_LEN   2048
#define D_DIM   64
#define BK      64

typedef __attribute__((ext_vector_type(8))) short  short8;
typedef __attribute__((ext_vector_type(4))) float  floatx4;

#define KLD   72   // K tile [64 keys][72] bf16, 144B rows
#define VTLD  72   // V^T tile [64 d][72] bf16
#define PLD   72   // P tile per wave [16 q][72] bf16
#define OLD   65   // epilogue fp32 transpose pitch

#define VTOFF 9216             // 64*72*2
#define POFF  18432            // 2*9216
#define SMEM_BYTES 27648       // 18432 + 4*16*72*2

__device__ __forceinline__ short f2bf(float x) {
  union { __hip_bfloat16 h; short s; } u;
  u.h = __float2bfloat16(x);
  return u.s;
}
__device__ __forceinline__ unsigned pk2(float lo, float hi) {
  union { __hip_bfloat16 h; unsigned short s; } a, b;
  a.h = __float2bfloat16(lo);
  b.h = __float2bfloat16(hi);
  return (unsigned)a.s | ((unsigned)b.s << 16);
}

__global__ __launch_bounds__(256, 4)
void fa_fwd(const float* __restrict__ Qg, const float* __restrict__ Kg,
            const float* __restrict__ Vg, float* __restrict__ Og)
{
  __shared__ char smem[SMEM_BYTES];
  short* Klds  = (short*)smem;
  short* Vtlds = (short*)(smem + VTOFF);

  const int tid  = threadIdx.x;
  const int wv   = tid >> 6;
  const int lane = tid & 63;
  const int col  = lane & 15;
  const int quad = lane >> 4;
  short* Plds = (short*)(smem + POFF) + wv * (16 * PLD);
  float* Olds = (float*)smem + wv * (16 * OLD);

  // big q-blocks dispatched first (they run qblk+1 iterations); same-bh blocks
  // recur at blockIdx stride 32 == 0 mod 8 -> same XCD -> K/V L2 reuse
  const int qblk = 31 - (blockIdx.x >> 5);
  const int bh   = blockIdx.x & 31;

  const float qscale = 0.18033688011112042f;   // log2(e)/sqrt(64): exp2-domain softmax
  const float* Kb = Kg + (size_t)bh * S_LEN * D_DIM;
  const float* Vb = Vg + (size_t)bh * S_LEN * D_DIM;
  const float* Qb = Qg + (size_t)bh * S_LEN * D_DIM;
  float*       Ob = Og + (size_t)bh * S_LEN * D_DIM;

  // staging thread mappings
  const int krow = tid >> 2;          // K: row (key) 0..63
  const int kcb  = (tid & 3) * 16;    // K: col base (d), 16 floats per thread
  const int kp2  = tid & 31;          // V: key-pair 0..31
  const int dbs  = (tid >> 5) * 8;    // V: d base, 8 d per thread

  float4 kr[4], vr[4];                // prefetch registers (next tile)

  const int q0  = qblk * 64;
  const int nit = qblk + 1;
  const int qw  = q0 + wv * 16;

  // ---- Q fragments (B-operand): b[j] = Q[q=col][d = h*32 + quad*8 + j] ----
  short8 qf[2];
#pragma unroll
  for (int h = 0; h < 2; ++h) {
    const float* qp = Qb + (size_t)(qw + col) * D_DIM + h * 32 + quad * 8;
    float4 a = *(const float4*)qp;
    float4 b = *(const float4*)(qp + 4);
    short8 f;
    f[0]=f2bf(a.x*qscale); f[1]=f2bf(a.y*qscale); f[2]=f2bf(a.z*qscale); f[3]=f2bf(a.w*qscale);
    f[4]=f2bf(b.x*qscale); f[5]=f2bf(b.y*qscale); f[6]=f2bf(b.z*qscale); f[7]=f2bf(b.w*qscale);
    qf[h] = f;
  }

  floatx4 o[4];
#pragma unroll
  for (int dt = 0; dt < 4; ++dt) o[dt] = (floatx4){0.f,0.f,0.f,0.f};
  float m_run = -3.0e38f, l_run = 0.f;

  // ---- prefetch tile 0 into registers ----
  {
    const float* p = Kb + (size_t)krow * D_DIM + kcb;
    kr[0] = *(const float4*)p;       kr[1] = *(const float4*)(p + 4);
    kr[2] = *(const float4*)(p + 8); kr[3] = *(const float4*)(p + 12);
    const float* pv = Vb + (size_t)(2 * kp2) * D_DIM + dbs;
    vr[0] = *(const float4*)pv;        vr[1] = *(const float4*)(pv + 4);
    vr[2] = *(const float4*)(pv + 64); vr[3] = *(const float4*)(pv + 68);
  }

  for (int it = 0; it < nit; ++it) {
    __syncthreads();                 // prev iter's LDS reads done

    // ---- regs -> LDS (bf16) ----
    {
      const float* f = (const float*)kr;
      short8 f0, f1;
      f0[0]=f2bf(f[0]);  f0[1]=f2bf(f[1]);  f0[2]=f2bf(f[2]);  f0[3]=f2bf(f[3]);
      f0[4]=f2bf(f[4]);  f0[5]=f2bf(f[5]);  f0[6]=f2bf(f[6]);  f0[7]=f2bf(f[7]);
      f1[0]=f2bf(f[8]);  f1[1]=f2bf(f[9]);  f1[2]=f2bf(f[10]); f1[3]=f2bf(f[11]);
      f1[4]=f2bf(f[12]); f1[5]=f2bf(f[13]); f1[6]=f2bf(f[14]); f1[7]=f2bf(f[15]);
      *(short8*)&Klds[krow * KLD + kcb]     = f0;
      *(short8*)&Klds[krow * KLD + kcb + 8] = f1;
      const float* g = (const float*)vr;   // g[0..7]=V[k0][d..], g[8..15]=V[k0+1][d..]
#pragma unroll
      for (int i = 0; i < 8; ++i)
        *(unsigned*)&Vtlds[(dbs + i) * VTLD + 2 * kp2] = pk2(g[i], g[8 + i]);
    }
    __syncthreads();

    // ---- prefetch next tile (stays in flight through compute) ----
    if (it + 1 < nit) {
      const int kb2 = (it + 1) * BK;
      const float* p = Kb + (size_t)(kb2 + krow) * D_DIM + kcb;
      kr[0] = *(const float4*)p;       kr[1] = *(const float4*)(p + 4);
      kr[2] = *(const float4*)(p + 8); kr[3] = *(const float4*)(p + 12);
      const float* pv = Vb + (size_t)(kb2 + 2 * kp2) * D_DIM + dbs;
      vr[0] = *(const float4*)pv;        vr[1] = *(const float4*)(pv + 4);
      vr[2] = *(const float4*)(pv + 64); vr[3] = *(const float4*)(pv + 68);
    }

    // ---- S^T = K · Q^T ----
    short8 kf[4][2];
#pragma unroll
    for (int kt = 0; kt < 4; ++kt)
#pragma unroll
      for (int h = 0; h < 2; ++h)
        kf[kt][h] = *(short8*)&Klds[(kt * 16 + col) * KLD + h * 32 + quad * 8];

    floatx4 st[4];
#pragma unroll
    for (int kt = 0; kt < 4; ++kt) {
      floatx4 c = (floatx4){0.f,0.f,0.f,0.f};
      c = __builtin_amdgcn_mfma_f32_16x16x32_bf16(kf[kt][0], qf[0], c, 0, 0, 0);
      c = __builtin_amdgcn_mfma_f32_16x16x32_bf16(kf[kt][1], qf[1], c, 0, 0, 0);
      st[kt] = c;
    }

    // ---- causal mask: only the diagonal (last) iteration needs it ----
    if (it == nit - 1) {
      const int qg = qw + col;
      const int kb = it * BK;
#pragma unroll
      for (int kt = 0; kt < 4; ++kt)
#pragma unroll
        for (int r = 0; r < 4; ++r)
          if (kb + kt * 16 + quad * 4 + r > qg) st[kt][r] = -3.0e38f;
    }

    // ---- online softmax (exp2 domain); keys live on quad -> 2 shuffles ----
    float mx = st[0][0];
#pragma unroll
    for (int kt = 0; kt < 4; ++kt)
#pragma unroll
      for (int r = 0; r < 4; ++r) mx = fmaxf(mx, st[kt][r]);
    mx = fmaxf(mx, __shfl_xor(mx, 16));
    mx = fmaxf(mx, __shfl_xor(mx, 32));
    const float mnew  = fmaxf(m_run, mx);
    const float alpha = __builtin_amdgcn_exp2f(m_run - mnew);
    m_run = mnew;
    float sum = 0.f;
#pragma unroll
    for (int kt = 0; kt < 4; ++kt)
#pragma unroll
      for (int r = 0; r < 4; ++r) {
        const float p = __builtin_amdgcn_exp2f(st[kt][r] - mnew);
        st[kt][r] = p;
        sum += p;
      }
    sum += __shfl_xor(sum, 16);
    sum += __shfl_xor(sum, 32);
    l_run = l_run * alpha + sum;
#pragma unroll
    for (int dt = 0; dt < 4; ++dt)
#pragma unroll
      for (int r = 0; r < 4; ++r) o[dt][r] *= alpha;

    // ---- P (C-layout) -> LDS P[q][k]; same-wave region, no barrier needed ----
#pragma unroll
    for (int kt = 0; kt < 4; ++kt) {
      *(unsigned*)&Plds[col * PLD + kt * 16 + quad * 4]     = pk2(st[kt][0], st[kt][1]);
      *(unsigned*)&Plds[col * PLD + kt * 16 + quad * 4 + 2] = pk2(st[kt][2], st[kt][3]);
    }
    short8 pf0 = *(short8*)&Plds[col * PLD + quad * 8];
    short8 pf1 = *(short8*)&Plds[col * PLD + 32 + quad * 8];

    // ---- O^T += V^T · P^T ----
#pragma unroll
    for (int dt = 0; dt < 4; ++dt) {
      short8 vf0 = *(short8*)&Vtlds[(dt * 16 + col) * VTLD + quad * 8];
      short8 vf1 = *(short8*)&Vtlds[(dt * 16 + col) * VTLD + 32 + quad * 8];
      o[dt] = __builtin_amdgcn_mfma_f32_16x16x32_bf16(vf0, pf0, o[dt], 0, 0, 0);
      o[dt] = __builtin_amdgcn_mfma_f32_16x16x32_bf16(vf1, pf1, o[dt], 0, 0, 0);
    }
  }

  // ---- epilogue: normalize, transpose via LDS, coalesced float4 stores ----
  __syncthreads();
  const float inv = 1.0f / l_run;
#pragma unroll
  for (int dt = 0; dt < 4; ++dt)
#pragma unroll
    for (int r = 0; r < 4; ++r)
      Olds[col * OLD + dt * 16 + quad * 4 + r] = o[dt][r] * inv;
#pragma unroll
  for (int it2 = 0; it2 < 4; ++it2) {
    const int ql = it2 * 4 + quad;
    float4 w;
    w.x = Olds[ql * OLD + col * 4 + 0];
    w.y = Olds[ql * OLD + col * 4 + 1];
    w.z = Olds[ql * OLD + col * 4 + 2];
    w.w = Olds[ql * OLD + col * 4 + 3];
    *(float4*)(Ob + (size_t)(qw + ql) * D_DIM + col * 4) = w;
  }
}

extern "C" void kernel_launch(void* const* d_in, const int* in_sizes, int n_in,
                              void* d_out, int out_size, void* d_ws, size_t ws_size,
                              hipStream_t stream) {
  const float* Q = (const float*)d_in[0];
  const float* K = (const float*)d_in[1];
  const float* V = (const float*)d_in[2];
  float* O = (float*)d_out;
  dim3 grid(32 * 32);   // 32 q-blocks (big first) x 32 (b*H+h)
  dim3 block(256);
  hipLaunchKernelGGL(fa_fwd, grid, block, 0, stream, Q, K, V, O);
}

// Round 4
// 144.956 us; speedup vs baseline: 1.1234x; 1.1234x over previous
//
#include <hip/hip_runtime.h>
#include <hip/hip_bf16.h>

#define S_LEN   2048
#define D_DIM   64
#define BK      64

typedef __attribute__((ext_vector_type(8))) short  short8;
typedef __attribute__((ext_vector_type(4))) float  floatx4;

#define KLD   72   // K tile [64 keys][72] bf16, 144B rows
#define VTLD  72   // V^T tile [64 d][72] bf16
#define PLD   72   // P tile per wave [16 q][72] bf16
#define OLD   65   // epilogue fp32 transpose pitch

#define VTOFF 9216             // 64*72*2
#define POFF  18432            // 2*9216
#define SMEM_BYTES 27648       // 18432 + 4*16*72*2

__device__ __forceinline__ short f2bf(float x) {
  union { __hip_bfloat16 h; short s; } u;
  u.h = __float2bfloat16(x);
  return u.s;
}
__device__ __forceinline__ unsigned pk2(float lo, float hi) {
  union { __hip_bfloat16 h; unsigned short s; } a, b;
  a.h = __float2bfloat16(lo);
  b.h = __float2bfloat16(hi);
  return (unsigned)a.s | ((unsigned)b.s << 16);
}

// (256,2): round-3's (256,4) forced VGPRs to 64 -> scratch spills (WRITE_SIZE
// 16MB->45MB). At 84 VGPRs / 27.6KB LDS, up to 5 blocks/CU are resident anyway.
__global__ __launch_bounds__(256, 2)
void fa_fwd(const float* __restrict__ Qg, const float* __restrict__ Kg,
            const float* __restrict__ Vg, float* __restrict__ Og)
{
  __shared__ char smem[SMEM_BYTES];
  short* Klds  = (short*)smem;
  short* Vtlds = (short*)(smem + VTOFF);

  const int tid  = threadIdx.x;
  const int wv   = tid >> 6;
  const int lane = tid & 63;
  const int col  = lane & 15;
  const int quad = lane >> 4;
  short* Plds = (short*)(smem + POFF) + wv * (16 * PLD);
  float* Olds = (float*)smem + wv * (16 * OLD);

  // big q-blocks dispatched first (they run qblk+1 iterations); same-bh blocks
  // recur at blockIdx stride 32 == 0 mod 8 -> same XCD -> K/V L2 reuse
  const int qblk = 31 - (blockIdx.x >> 5);
  const int bh   = blockIdx.x & 31;

  const float qscale = 0.18033688011112042f;   // log2(e)/sqrt(64): exp2-domain softmax
  const float* Kb = Kg + (size_t)bh * S_LEN * D_DIM;
  const float* Vb = Vg + (size_t)bh * S_LEN * D_DIM;
  const float* Qb = Qg + (size_t)bh * S_LEN * D_DIM;
  float*       Ob = Og + (size_t)bh * S_LEN * D_DIM;

  // staging thread mappings
  const int krow = tid >> 2;          // K: row (key) 0..63
  const int kcb  = (tid & 3) * 16;    // K: col base (d), 16 floats per thread
  const int kp2  = tid & 31;          // V: key-pair 0..31
  const int dbs  = (tid >> 5) * 8;    // V: d base, 8 d per thread

  float4 kr[4], vr[4];                // prefetch registers (next tile)

  const int q0  = qblk * 64;
  const int nit = qblk + 1;
  const int qw  = q0 + wv * 16;

  // ---- Q fragments (B-operand): b[j] = Q[q=col][d = h*32 + quad*8 + j] ----
  short8 qf[2];
#pragma unroll
  for (int h = 0; h < 2; ++h) {
    const float* qp = Qb + (size_t)(qw + col) * D_DIM + h * 32 + quad * 8;
    float4 a = *(const float4*)qp;
    float4 b = *(const float4*)(qp + 4);
    short8 f;
    f[0]=f2bf(a.x*qscale); f[1]=f2bf(a.y*qscale); f[2]=f2bf(a.z*qscale); f[3]=f2bf(a.w*qscale);
    f[4]=f2bf(b.x*qscale); f[5]=f2bf(b.y*qscale); f[6]=f2bf(b.z*qscale); f[7]=f2bf(b.w*qscale);
    qf[h] = f;
  }

  floatx4 o[4];
#pragma unroll
  for (int dt = 0; dt < 4; ++dt) o[dt] = (floatx4){0.f,0.f,0.f,0.f};
  float m_run = -3.0e38f, l_run = 0.f;

  // ---- prefetch tile 0 into registers ----
  {
    const float* p = Kb + (size_t)krow * D_DIM + kcb;
    kr[0] = *(const float4*)p;       kr[1] = *(const float4*)(p + 4);
    kr[2] = *(const float4*)(p + 8); kr[3] = *(const float4*)(p + 12);
    const float* pv = Vb + (size_t)(2 * kp2) * D_DIM + dbs;
    vr[0] = *(const float4*)pv;        vr[1] = *(const float4*)(pv + 4);
    vr[2] = *(const float4*)(pv + 64); vr[3] = *(const float4*)(pv + 68);
  }

  for (int it = 0; it < nit; ++it) {
    __syncthreads();                 // prev iter's LDS reads done

    // ---- regs -> LDS (bf16) ----
    {
      const float* f = (const float*)kr;
      short8 f0, f1;
      f0[0]=f2bf(f[0]);  f0[1]=f2bf(f[1]);  f0[2]=f2bf(f[2]);  f0[3]=f2bf(f[3]);
      f0[4]=f2bf(f[4]);  f0[5]=f2bf(f[5]);  f0[6]=f2bf(f[6]);  f0[7]=f2bf(f[7]);
      f1[0]=f2bf(f[8]);  f1[1]=f2bf(f[9]);  f1[2]=f2bf(f[10]); f1[3]=f2bf(f[11]);
      f1[4]=f2bf(f[12]); f1[5]=f2bf(f[13]); f1[6]=f2bf(f[14]); f1[7]=f2bf(f[15]);
      *(short8*)&Klds[krow * KLD + kcb]     = f0;
      *(short8*)&Klds[krow * KLD + kcb + 8] = f1;
      const float* g = (const float*)vr;   // g[0..7]=V[k0][d..], g[8..15]=V[k0+1][d..]
#pragma unroll
      for (int i = 0; i < 8; ++i)
        *(unsigned*)&Vtlds[(dbs + i) * VTLD + 2 * kp2] = pk2(g[i], g[8 + i]);
    }
    __syncthreads();

    // ---- prefetch next tile (stays in flight through compute) ----
    if (it + 1 < nit) {
      const int kb2 = (it + 1) * BK;
      const float* p = Kb + (size_t)(kb2 + krow) * D_DIM + kcb;
      kr[0] = *(const float4*)p;       kr[1] = *(const float4*)(p + 4);
      kr[2] = *(const float4*)(p + 8); kr[3] = *(const float4*)(p + 12);
      const float* pv = Vb + (size_t)(kb2 + 2 * kp2) * D_DIM + dbs;
      vr[0] = *(const float4*)pv;        vr[1] = *(const float4*)(pv + 4);
      vr[2] = *(const float4*)(pv + 64); vr[3] = *(const float4*)(pv + 68);
    }

    // ---- S^T = K · Q^T ----
    short8 kf[4][2];
#pragma unroll
    for (int kt = 0; kt < 4; ++kt)
#pragma unroll
      for (int h = 0; h < 2; ++h)
        kf[kt][h] = *(short8*)&Klds[(kt * 16 + col) * KLD + h * 32 + quad * 8];

    floatx4 st[4];
#pragma unroll
    for (int kt = 0; kt < 4; ++kt) {
      floatx4 c = (floatx4){0.f,0.f,0.f,0.f};
      c = __builtin_amdgcn_mfma_f32_16x16x32_bf16(kf[kt][0], qf[0], c, 0, 0, 0);
      c = __builtin_amdgcn_mfma_f32_16x16x32_bf16(kf[kt][1], qf[1], c, 0, 0, 0);
      st[kt] = c;
    }

    // ---- causal mask: only the diagonal (last) iteration needs it ----
    if (it == nit - 1) {
      const int qg = qw + col;
      const int kb = it * BK;
#pragma unroll
      for (int kt = 0; kt < 4; ++kt)
#pragma unroll
        for (int r = 0; r < 4; ++r)
          if (kb + kt * 16 + quad * 4 + r > qg) st[kt][r] = -3.0e38f;
    }

    // ---- online softmax (exp2 domain); keys live on quad -> 2 shuffles ----
    float mx = st[0][0];
#pragma unroll
    for (int kt = 0; kt < 4; ++kt)
#pragma unroll
      for (int r = 0; r < 4; ++r) mx = fmaxf(mx, st[kt][r]);
    mx = fmaxf(mx, __shfl_xor(mx, 16));
    mx = fmaxf(mx, __shfl_xor(mx, 32));
    const float mnew  = fmaxf(m_run, mx);
    const float alpha = __builtin_amdgcn_exp2f(m_run - mnew);
    m_run = mnew;
    float sum = 0.f;
#pragma unroll
    for (int kt = 0; kt < 4; ++kt)
#pragma unroll
      for (int r = 0; r < 4; ++r) {
        const float p = __builtin_amdgcn_exp2f(st[kt][r] - mnew);
        st[kt][r] = p;
        sum += p;
      }
    sum += __shfl_xor(sum, 16);
    sum += __shfl_xor(sum, 32);
    l_run = l_run * alpha + sum;
#pragma unroll
    for (int dt = 0; dt < 4; ++dt)
#pragma unroll
      for (int r = 0; r < 4; ++r) o[dt][r] *= alpha;

    // ---- P (C-layout) -> LDS P[q][k]; same-wave region, no barrier needed ----
#pragma unroll
    for (int kt = 0; kt < 4; ++kt) {
      *(unsigned*)&Plds[col * PLD + kt * 16 + quad * 4]     = pk2(st[kt][0], st[kt][1]);
      *(unsigned*)&Plds[col * PLD + kt * 16 + quad * 4 + 2] = pk2(st[kt][2], st[kt][3]);
    }
    short8 pf0 = *(short8*)&Plds[col * PLD + quad * 8];
    short8 pf1 = *(short8*)&Plds[col * PLD + 32 + quad * 8];

    // ---- O^T += V^T · P^T ----
#pragma unroll
    for (int dt = 0; dt < 4; ++dt) {
      short8 vf0 = *(short8*)&Vtlds[(dt * 16 + col) * VTLD + quad * 8];
      short8 vf1 = *(short8*)&Vtlds[(dt * 16 + col) * VTLD + 32 + quad * 8];
      o[dt] = __builtin_amdgcn_mfma_f32_16x16x32_bf16(vf0, pf0, o[dt], 0, 0, 0);
      o[dt] = __builtin_amdgcn_mfma_f32_16x16x32_bf16(vf1, pf1, o[dt], 0, 0, 0);
    }
  }

  // ---- epilogue: normalize, transpose via LDS, coalesced float4 stores ----
  __syncthreads();
  const float inv = 1.0f / l_run;
#pragma unroll
  for (int dt = 0; dt < 4; ++dt)
#pragma unroll
    for (int r = 0; r < 4; ++r)
      Olds[col * OLD + dt * 16 + quad * 4 + r] = o[dt][r] * inv;
#pragma unroll
  for (int it2 = 0; it2 < 4; ++it2) {
    const int ql = it2 * 4 + quad;
    float4 w;
    w.x = Olds[ql * OLD + col * 4 + 0];
    w.y = Olds[ql * OLD + col * 4 + 1];
    w.z = Olds[ql * OLD + col * 4 + 2];
    w.w = Olds[ql * OLD + col * 4 + 3];
    *(float4*)(Ob + (size_t)(qw + ql) * D_DIM + col * 4) = w;
  }
}

extern "C" void kernel_launch(void* const* d_in, const int* in_sizes, int n_in,
                              void* d_out, int out_size, void* d_ws, size_t ws_size,
                              hipStream_t stream) {
  const float* Q = (const float*)d_in[0];
  const float* K = (const float*)d_in[1];
  const float* V = (const float*)d_in[2];
  float* O = (float*)d_out;
  dim3 grid(32 * 32);   // 32 q-blocks (big first) x 32 (b*H+h)
  dim3 block(256);
  hipLaunchKernelGGL(fa_fwd, grid, block, 0, stream, Q, K, V, O);
}